// Round 8
// baseline (130.105 us; speedup 1.0000x reference)
//
#include <hip/hip_runtime.h>
#include <hip/hip_bf16.h>
#include <stdint.h>

typedef unsigned short ushort_t;
typedef __attribute__((ext_vector_type(8))) short short8;      // 8 bf16 (MFMA A/B frag)
typedef __attribute__((ext_vector_type(4))) ushort_t ushort4v; // packed bf16 x4 (8B)
typedef __attribute__((ext_vector_type(4))) float float4v;
typedef __attribute__((ext_vector_type(16))) float floatx16;   // 32x32 MFMA C/D frag

#define MFMA32(a, b, c) __builtin_amdgcn_mfma_f32_32x32x16_bf16(a, b, c, 0, 0, 0)

// ---- problem constants ----
#define BATCH 4
#define SEQ 4096
#define DIM 256
#define HEADS 4
#define DHEAD 64
#define INNER 256
#define MROWS (BATCH * SEQ)   // 16384
#define NQKV (3 * INNER)      // 768

__device__ __forceinline__ ushort_t f2bf(float f) {
    uint32_t u = __builtin_bit_cast(uint32_t, f);
    uint32_t r = (u + 0x7FFFu + ((u >> 16) & 1u)) >> 16;
    return (ushort_t)r;
}

__device__ __forceinline__ float exp2_fast(float x) {
#if __has_builtin(__builtin_amdgcn_exp2f)
    return __builtin_amdgcn_exp2f(x);
#else
    return exp2f(x);
#endif
}

__device__ __forceinline__ float max3f(float a, float b, float c) {
    return fmaxf(fmaxf(a, b), c);
}

__device__ __forceinline__ unsigned cvtpk_bf16(float lo, float hi) {
    unsigned r;
    asm("v_cvt_pk_bf16_f32 %0, %1, %2" : "=v"(r) : "v"(lo), "v"(hi));
    return r;
}

__device__ __forceinline__ void plswap(unsigned& a, unsigned& b) {
#if __has_builtin(__builtin_amdgcn_permlane32_swap)
    auto rr = __builtin_amdgcn_permlane32_swap(a, b, false, false);
    a = (unsigned)rr[0];
    b = (unsigned)rr[1];
#else
    unsigned sa = (unsigned)__shfl_xor((int)a, 32, 64);
    unsigned sb = (unsigned)__shfl_xor((int)b, 32, 64);
    bool upper = (threadIdx.x & 32) != 0;
    unsigned na = upper ? sb : a;
    unsigned nb = upper ? b : sa;
    a = na;
    b = nb;
#endif
}

// async 16B global -> LDS (wave-uniform LDS base + lane*16 dest; per-lane global src)
__device__ __forceinline__ void gload_lds16(const ushort_t* g, ushort_t* l) {
    __builtin_amdgcn_global_load_lds(
        (__attribute__((address_space(1))) void*)(const_cast<ushort_t*>(g)),
        (__attribute__((address_space(3))) void*)l, 16, 0, 0);
}

// ---------------- stage 0: fp32 -> bf16 conversion (weights only) ----------------
__global__ __launch_bounds__(256) void convert_w(
    const float* __restrict__ wqkv, const float* __restrict__ wout,
    ushort_t* __restrict__ wqkvb, ushort_t* __restrict__ woutb) {
    const int NW = NQKV * DIM;   // 196608
    const int NO = DIM * INNER;  // 65536
    const float QS = 0.125f * 1.4426950408889634f;  // scale * log2(e)
    int idx = blockIdx.x * blockDim.x + threadIdx.x;
    int stride = gridDim.x * blockDim.x;
    for (int i = idx; i < NW + NO; i += stride) {
        if (i < NW) {
            float s = (i < INNER * DIM) ? QS : 1.0f;
            wqkvb[i] = f2bf(wqkv[i] * s);
        } else {
            int j = i - NW;
            woutb[j] = f2bf(wout[j]);
        }
    }
}

// ---------------- stage 1: qkv = x @ w_qkv^T (fp32 x read direct, packed in-reg) --------
__global__ __launch_bounds__(256) void qkv_gemm(
    const float* __restrict__ X, const ushort_t* __restrict__ B,
    ushort_t* __restrict__ q, ushort_t* __restrict__ k, ushort_t* __restrict__ v) {
    __shared__ ushort_t Bs[128 * 256] __attribute__((aligned(16)));  // 64 KB
    int bid = blockIdx.x;
    int swz = (bid & 7) * 96 + (bid >> 3);   // 768 = 8 * 96, bijective
    int mt = swz / 6, nb = swz % 6;
    int tid = threadIdx.x;
    int wid = tid >> 6, lane = tid & 63;
    const int l31 = lane & 31, hi = lane >> 5;

    const ushort_t* bsrc = B + (int64_t)nb * 128 * 256;
#pragma unroll
    for (int i = 0; i < 16; ++i) {
        int L = i * 256 + tid;
        int sl = L ^ ((L >> 5) & 31);   // involution (bits0-4 ^= bits5-9)
        gload_lds16(bsrc + (sl >> 5) * 256 + (sl & 31) * 8, &Bs[L * 8]);
    }

    int m0 = mt * 128 + wid * 32;
    const float* abase = X + (int64_t)(m0 + l31) * 256 + hi * 8;
    short8 af[16];
#pragma unroll
    for (int s = 0; s < 16; ++s) {
        float4v a0 = *(const float4v*)(abase + s * 16);
        float4v a1 = *(const float4v*)(abase + s * 16 + 4);
        union { unsigned u[4]; short8 s8; } fu;
        fu.u[0] = cvtpk_bf16(a0[0], a0[1]);
        fu.u[1] = cvtpk_bf16(a0[2], a0[3]);
        fu.u[2] = cvtpk_bf16(a1[0], a1[1]);
        fu.u[3] = cvtpk_bf16(a1[2], a1[3]);
        af[s] = fu.s8;
    }

    __syncthreads();

    floatx16 acc[4] = {};
    __builtin_amdgcn_s_setprio(1);
#pragma unroll
    for (int s = 0; s < 16; ++s) {
#pragma unroll
        for (int nt = 0; nt < 4; ++nt) {
            int n = nt * 32 + l31;
            int byte = (n * 512 + s * 32 + hi * 16) ^ ((n & 31) << 4);
            short8 bf = *(const short8*)((const char*)Bs + byte);
            acc[nt] = MFMA32(af[s], bf, acc[nt]);
        }
    }
    __builtin_amdgcn_s_setprio(0);

    int part = nb >> 1;   // 0=q, 1=k, 2=v
    if (part < 2) {
        ushort_t* dst = (part == 0) ? q : k;
#pragma unroll
        for (int nt = 0; nt < 4; ++nt) {
            int cc = (nb * 128 + nt * 32 + l31) & 255;
            int h = cc >> 6, d = cc & 63;
#pragma unroll
            for (int r = 0; r < 16; ++r) {
                int m = m0 + (r & 3) + 8 * (r >> 2) + 4 * hi;
                int bb = m >> 12, n = m & 4095;
                dst[((((int64_t)bb * HEADS + h) * SEQ) + n) * DHEAD + d] = f2bf(acc[nt][r]);
            }
        }
    } else {
#pragma unroll
        for (int nt = 0; nt < 4; ++nt) {
            int cc = (nb * 128 + nt * 32 + l31) & 255;
            int h = cc >> 6, d = cc & 63;
#pragma unroll
            for (int g = 0; g < 4; ++g) {
                int m = m0 + g * 8 + hi * 4;
                int bb = m >> 12, n = m & 4095;
                ushort4v pk;
#pragma unroll
                for (int r = 0; r < 4; ++r) pk[r] = f2bf(acc[nt][g * 4 + r]);
                *(ushort4v*)(v + ((((int64_t)bb * HEADS + h) * DHEAD) + d) * SEQ + n) = pk;
            }
        }
    }
}

// ---------------- stage 2: flash attention — ROUND-5 VERBATIM (known-good) ----------------
// grid = 512 (16 bh * 32 q-tiles of 128); 4 waves, each owns 32 q rows; KVBLK=128.
__global__ __launch_bounds__(256, 2) void attn_kernel(
    const ushort_t* __restrict__ Qg, const ushort_t* __restrict__ Kg,
    const ushort_t* __restrict__ Vtg, ushort_t* __restrict__ Og) {
    int bid = blockIdx.x;
    int swz = (bid & 7) * 64 + (bid >> 3);   // XCD-aware, bijective (512 % 8 == 0)
    int bh = swz >> 5;   // 0..15
    int qt = swz & 31;   // 0..31
    int tid = threadIdx.x;
    int wid = tid >> 6, lane = tid & 63;
    const int l31 = lane & 31;
    const int hi = lane >> 5;

    __shared__ ushort_t SM[2][16384] __attribute__((aligned(16)));  // 64 KB

    const ushort_t* qbase = Qg + (int64_t)bh * SEQ * DHEAD;
    const ushort_t* kbase = Kg + (int64_t)bh * SEQ * DHEAD;
    const ushort_t* vtbase = Vtg + (int64_t)bh * DHEAD * SEQ;

    int q0 = qt * 128 + wid * 32;
    short8 qf[4];
#pragma unroll
    for (int s = 0; s < 4; ++s)
        qf[s] = *(const short8*)(qbase + (int64_t)(q0 + l31) * DHEAD + s * 16 + hi * 8);

    const ushort_t* kp[4];
    const ushort_t* vp[4];
    ushort_t* kld[4];
    ushort_t* vld[4];
#pragma unroll
    for (int jj = 0; jj < 4; ++jj) {
        int L = jj * 256 + tid;
        int sl = L ^ ((L >> 7) & 7);   // involution
        int s_ = sl >> 8, hi_ = (sl >> 7) & 1, key_ = sl & 127;
        kp[jj] = kbase + key_ * DHEAD + s_ * 16 + hi_ * 8;
        int ks_ = sl >> 7, hik_ = (sl >> 6) & 1, d_ = sl & 63;
        vp[jj] = vtbase + (int64_t)d_ * SEQ + ks_ * 16 + hik_ * 8;
        kld[jj] = &SM[0][(jj * 256 + wid * 64) * 8];
        vld[jj] = &SM[0][8192 + (jj * 256 + wid * 64) * 8];
    }

#define STAGE(BUF)                                           \
    {                                                        \
        _Pragma("unroll") for (int jj = 0; jj < 4; ++jj) {   \
            gload_lds16(kp[jj], kld[jj] + (BUF) * 16384);    \
            gload_lds16(vp[jj], vld[jj] + (BUF) * 16384);    \
            kp[jj] += 128 * DHEAD;                           \
            vp[jj] += 128;                                   \
        }                                                    \
    }

    int bS[4];
#pragma unroll
    for (int s = 0; s < 4; ++s) bS[s] = hi * 2048 + ((l31 * 16) ^ ((s * 2 + hi) << 4));
    const int tV = hi * 1024 + l31 * 16;

    floatx16 accO[2] = {};
    floatx16 mseed = {};              // all elements = -m_i
    float m_i = 0.f, l_i = 0.f;       // exp2-space; 0-init valid with defer-max

    STAGE(0);
    __syncthreads();

    for (int it = 0; it < SEQ / 128; ++it) {
        int buf = it & 1;
        const char* smc = (const char*)SM + buf * 32768;
        const char* smv = smc + 16384;
        if (it < SEQ / 128 - 1) STAGE(buf ^ 1);

        // --- S^T = K @ Q^T, C seeded with mseed = -m_i ---
        floatx16 accS[4];
        __builtin_amdgcn_s_setprio(1);
#pragma unroll
        for (int s = 0; s < 4; ++s) {
#pragma unroll
            for (int kt = 0; kt < 4; ++kt) {
                short8 kf = *(const short8*)(smc + bS[s] + s * 4096 + kt * 512);
                accS[kt] = MFMA32(kf, qf[s], s == 0 ? mseed : accS[kt]);
            }
        }
        __builtin_amdgcn_s_setprio(0);

        // --- max over 64 biased scores ---
        float mk[4];
#pragma unroll
        for (int kt = 0; kt < 4; ++kt) {
            float t0 = max3f(accS[kt][0], accS[kt][1], accS[kt][2]);
            t0 = max3f(t0, accS[kt][3], accS[kt][4]);
            t0 = max3f(t0, accS[kt][5], accS[kt][6]);
            t0 = max3f(t0, accS[kt][7], accS[kt][8]);
            t0 = max3f(t0, accS[kt][9], accS[kt][10]);
            t0 = max3f(t0, accS[kt][11], accS[kt][12]);
            t0 = max3f(t0, accS[kt][13], accS[kt][14]);
            mk[kt] = fmaxf(t0, accS[kt][15]);
        }
        float mx = fmaxf(max3f(mk[0], mk[1], mk[2]), mk[3]);
        mx = fmaxf(mx, __shfl_xor(mx, 32, 64));

        // --- defer-max rescale (rare) ---
        if (!__all(mx <= 8.f)) {
            float mb = fmaxf(mx, 0.f);
            float corr = exp2_fast(-mb);
            l_i *= corr;
#pragma unroll
            for (int r = 0; r < 16; ++r) {
                int qr = (r & 3) + 8 * (r >> 2) + 4 * hi;
                float cr = __shfl(corr, qr, 64);
                accO[0][r] *= cr;
                accO[1][r] *= cr;
            }
            m_i += mb;
#pragma unroll
            for (int r = 0; r < 16; ++r) mseed[r] -= mb;
#pragma unroll
            for (int kt = 0; kt < 4; ++kt)
#pragma unroll
                for (int r = 0; r < 16; ++r) accS[kt][r] -= mb;
        }

        // --- exp2 + row-sum ---
        float rs0 = 0.f, rs1 = 0.f, rs2 = 0.f, rs3 = 0.f;
#pragma unroll
        for (int r = 0; r < 16; ++r) {
            float e0 = exp2_fast(accS[0][r]);
            float e1 = exp2_fast(accS[1][r]);
            float e2 = exp2_fast(accS[2][r]);
            float e3 = exp2_fast(accS[3][r]);
            accS[0][r] = e0;
            accS[1][r] = e1;
            accS[2][r] = e2;
            accS[3][r] = e3;
            rs0 += e0;
            rs1 += e1;
            rs2 += e2;
            rs3 += e3;
        }
        float rs = (rs0 + rs1) + (rs2 + rs3);
        rs += __shfl_xor(rs, 32, 64);
        l_i += rs;

        // --- pack P to bf16, assemble PV A-frags in-register ---
        short8 pa[8];
#pragma unroll
        for (int kt = 0; kt < 4; ++kt) {
            unsigned w0 = cvtpk_bf16(accS[kt][0], accS[kt][1]);
            unsigned w1 = cvtpk_bf16(accS[kt][2], accS[kt][3]);
            unsigned w2 = cvtpk_bf16(accS[kt][4], accS[kt][5]);
            unsigned w3 = cvtpk_bf16(accS[kt][6], accS[kt][7]);
            unsigned w4 = cvtpk_bf16(accS[kt][8], accS[kt][9]);
            unsigned w5 = cvtpk_bf16(accS[kt][10], accS[kt][11]);
            unsigned w6 = cvtpk_bf16(accS[kt][12], accS[kt][13]);
            unsigned w7 = cvtpk_bf16(accS[kt][14], accS[kt][15]);
            plswap(w0, w2);
            plswap(w1, w3);
            plswap(w4, w6);
            plswap(w5, w7);
            union { unsigned u[4]; short8 s; } f0, f1;
            f0.u[0] = w0; f0.u[1] = w1; f0.u[2] = w2; f0.u[3] = w3;
            f1.u[0] = w4; f1.u[1] = w5; f1.u[2] = w6; f1.u[3] = w7;
            pa[2 * kt] = f0.s;
            pa[2 * kt + 1] = f1.s;
        }

        // --- O += P @ V ---
        __builtin_amdgcn_s_setprio(1);
#pragma unroll
        for (int ks = 0; ks < 8; ++ks) {
            int va = tV ^ (ks << 4);
#pragma unroll
            for (int o = 0; o < 2; ++o) {
                short8 vf = *(const short8*)(smv + va + ks * 2048 + o * 512);
                accO[o] = MFMA32(pa[ks], vf, accO[o]);
            }
        }
        __builtin_amdgcn_s_setprio(0);

        __syncthreads();
    }

    // --- epilogue: normalize, write O as [b, n, h*64+d] bf16 ---
    int b = bh >> 2, h = bh & 3;
    float invl = 1.f / l_i;
#pragma unroll
    for (int r = 0; r < 16; ++r) {
        int qr = (r & 3) + 8 * (r >> 2) + 4 * hi;
        float inv = __shfl(invl, qr, 64);
        int n = q0 + qr;
#pragma unroll
        for (int o = 0; o < 2; ++o) {
            int d = o * 32 + l31;
            Og[((int64_t)b * SEQ + n) * INNER + h * 64 + d] = f2bf(accO[o][r] * inv);
        }
    }
#undef STAGE
}

// ---------------- stage 3: out = O @ w_out^T + b_out (block-tiled, LDS-staged B) --------
__global__ __launch_bounds__(256) void proj_gemm(
    const ushort_t* __restrict__ A, const ushort_t* __restrict__ B,
    const float* __restrict__ bias, float* __restrict__ out) {
    __shared__ ushort_t Bs[128 * 256] __attribute__((aligned(16)));  // 64 KB
    int bid = blockIdx.x;
    int swz = (bid & 7) * 64 + (bid >> 3);   // 512 = 8 * 64
    int mt = swz >> 1, nb = swz & 1;
    int tid = threadIdx.x;
    int wid = tid >> 6, lane = tid & 63;
    const int l31 = lane & 31, hi = lane >> 5;

    const ushort_t* bsrc = B + (int64_t)nb * 128 * 256;
#pragma unroll
    for (int i = 0; i < 16; ++i) {
        int L = i * 256 + tid;
        int sl = L ^ ((L >> 5) & 31);
        gload_lds16(bsrc + (sl >> 5) * 256 + (sl & 31) * 8, &Bs[L * 8]);
    }

    int m0 = mt * 64 + (wid & 1) * 32;
    int nside = wid >> 1;
    const ushort_t* abase = A + (int64_t)(m0 + l31) * 256 + hi * 8;
    short8 af[16];
#pragma unroll
    for (int s = 0; s < 16; ++s) af[s] = *(const short8*)(abase + s * 16);

    __syncthreads();

    floatx16 acc[2] = {};
    __builtin_amdgcn_s_setprio(1);
#pragma unroll
    for (int s = 0; s < 16; ++s) {
#pragma unroll
        for (int nt = 0; nt < 2; ++nt) {
            int n = nside * 64 + nt * 32 + l31;
            int byte = (n * 512 + s * 32 + hi * 16) ^ ((n & 31) << 4);
            short8 bf = *(const short8*)((const char*)Bs + byte);
            acc[nt] = MFMA32(af[s], bf, acc[nt]);
        }
    }
    __builtin_amdgcn_s_setprio(0);

#pragma unroll
    for (int nt = 0; nt < 2; ++nt) {
        int col = nb * 128 + nside * 64 + nt * 32 + l31;
        float bv = bias[col];
#pragma unroll
        for (int r = 0; r < 16; ++r) {
            int m = m0 + (r & 3) + 8 * (r >> 2) + 4 * hi;
            out[(int64_t)m * DIM + col] = acc[nt][r] + bv;
        }
    }
}

extern "C" void kernel_launch(void* const* d_in, const int* in_sizes, int n_in,
                              void* d_out, int out_size, void* d_ws, size_t ws_size,
                              hipStream_t stream) {
    const float* x = (const float*)d_in[0];
    const float* w_qkv = (const float*)d_in[1];
    const float* w_out = (const float*)d_in[2];
    const float* b_out = (const float*)d_in[3];
    float* out = (float*)d_out;

    ushort_t* ws = (ushort_t*)d_ws;
    const int64_t NW = (int64_t)NQKV * DIM;        // 196608
    const int64_t NO = (int64_t)DIM * INNER;       // 65536
    const int64_t NH = (int64_t)BATCH * HEADS * SEQ * DHEAD;  // 4194304
    ushort_t* wqkvb = ws;
    ushort_t* woutb = wqkvb + NW;
    ushort_t* qb = woutb + NO;
    ushort_t* kb = qb + NH;
    ushort_t* vb = kb + NH;      // V^T layout [b,h,d,n]
    ushort_t* ob = vb + NH;

    convert_w<<<256, 256, 0, stream>>>(w_qkv, w_out, wqkvb, woutb);
    qkv_gemm<<<768, 256, 0, stream>>>(x, wqkvb, qb, kb, vb);
    attn_kernel<<<512, 256, 0, stream>>>(qb, kb, vb, ob);
    proj_gemm<<<512, 256, 0, stream>>>(ob, woutb, b_out, out);
}

// Round 9
// 126.813 us; speedup vs baseline: 1.0260x; 1.0260x over previous
//
#include <hip/hip_runtime.h>
#include <hip/hip_bf16.h>
#include <stdint.h>

typedef unsigned short ushort_t;
typedef __attribute__((ext_vector_type(8))) short short8;      // 8 bf16 (MFMA A/B frag)
typedef __attribute__((ext_vector_type(4))) ushort_t ushort4v; // packed bf16 x4 (8B)
typedef __attribute__((ext_vector_type(4))) float float4v;
typedef __attribute__((ext_vector_type(16))) float floatx16;   // 32x32 MFMA C/D frag

#define MFMA32(a, b, c) __builtin_amdgcn_mfma_f32_32x32x16_bf16(a, b, c, 0, 0, 0)

// ---- problem constants ----
#define BATCH 4
#define SEQ 4096
#define DIM 256
#define HEADS 4
#define DHEAD 64
#define INNER 256
#define MROWS (BATCH * SEQ)   // 16384
#define NQKV (3 * INNER)      // 768

__device__ __forceinline__ ushort_t f2bf(float f) {
    uint32_t u = __builtin_bit_cast(uint32_t, f);
    uint32_t r = (u + 0x7FFFu + ((u >> 16) & 1u)) >> 16;
    return (ushort_t)r;
}

__device__ __forceinline__ float exp2_fast(float x) {
#if __has_builtin(__builtin_amdgcn_exp2f)
    return __builtin_amdgcn_exp2f(x);
#else
    return exp2f(x);
#endif
}

__device__ __forceinline__ float max3f(float a, float b, float c) {
    return fmaxf(fmaxf(a, b), c);
}

__device__ __forceinline__ unsigned cvtpk_bf16(float lo, float hi) {
    unsigned r;
    asm("v_cvt_pk_bf16_f32 %0, %1, %2" : "=v"(r) : "v"(lo), "v"(hi));
    return r;
}

__device__ __forceinline__ void plswap(unsigned& a, unsigned& b) {
#if __has_builtin(__builtin_amdgcn_permlane32_swap)
    auto rr = __builtin_amdgcn_permlane32_swap(a, b, false, false);
    a = (unsigned)rr[0];
    b = (unsigned)rr[1];
#else
    unsigned sa = (unsigned)__shfl_xor((int)a, 32, 64);
    unsigned sb = (unsigned)__shfl_xor((int)b, 32, 64);
    bool upper = (threadIdx.x & 32) != 0;
    unsigned na = upper ? sb : a;
    unsigned nb = upper ? b : sa;
    a = na;
    b = nb;
#endif
}

// async 16B global -> LDS (wave-uniform LDS base + lane*16 dest; per-lane global src)
__device__ __forceinline__ void gload_lds16(const ushort_t* g, ushort_t* l) {
    __builtin_amdgcn_global_load_lds(
        (__attribute__((address_space(1))) void*)(const_cast<ushort_t*>(g)),
        (__attribute__((address_space(3))) void*)l, 16, 0, 0);
}

// ---------------- stage 0: fp32 -> bf16 conversion (weights only) ----------------
__global__ __launch_bounds__(256) void convert_w(
    const float* __restrict__ wqkv, const float* __restrict__ wout,
    ushort_t* __restrict__ wqkvb, ushort_t* __restrict__ woutb) {
    const int NW = NQKV * DIM;   // 196608
    const int NO = DIM * INNER;  // 65536
    const float QS = 0.125f * 1.4426950408889634f;  // scale * log2(e)
    int idx = blockIdx.x * blockDim.x + threadIdx.x;
    int stride = gridDim.x * blockDim.x;
    for (int i = idx; i < NW + NO; i += stride) {
        if (i < NW) {
            float s = (i < INNER * DIM) ? QS : 1.0f;
            wqkvb[i] = f2bf(wqkv[i] * s);
        } else {
            int j = i - NW;
            woutb[j] = f2bf(wout[j]);
        }
    }
}

// ---------------- stage 1: qkv = x @ w_qkv^T (fp32 x read direct, packed in-reg) --------
__global__ __launch_bounds__(256) void qkv_gemm(
    const float* __restrict__ X, const ushort_t* __restrict__ B,
    ushort_t* __restrict__ q, ushort_t* __restrict__ k, ushort_t* __restrict__ v) {
    __shared__ ushort_t Bs[128 * 256] __attribute__((aligned(16)));  // 64 KB
    int bid = blockIdx.x;
    int swz = (bid & 7) * 96 + (bid >> 3);   // 768 = 8 * 96, bijective
    int mt = swz / 6, nb = swz % 6;
    int tid = threadIdx.x;
    int wid = tid >> 6, lane = tid & 63;
    const int l31 = lane & 31, hi = lane >> 5;

    const ushort_t* bsrc = B + (int64_t)nb * 128 * 256;
#pragma unroll
    for (int i = 0; i < 16; ++i) {
        int L = i * 256 + tid;
        int sl = L ^ ((L >> 5) & 31);   // involution (bits0-4 ^= bits5-9)
        gload_lds16(bsrc + (sl >> 5) * 256 + (sl & 31) * 8, &Bs[L * 8]);
    }

    int m0 = mt * 128 + wid * 32;
    const float* abase = X + (int64_t)(m0 + l31) * 256 + hi * 8;
    short8 af[16];
#pragma unroll
    for (int s = 0; s < 16; ++s) {
        float4v a0 = *(const float4v*)(abase + s * 16);
        float4v a1 = *(const float4v*)(abase + s * 16 + 4);
        union { unsigned u[4]; short8 s8; } fu;
        fu.u[0] = cvtpk_bf16(a0[0], a0[1]);
        fu.u[1] = cvtpk_bf16(a0[2], a0[3]);
        fu.u[2] = cvtpk_bf16(a1[0], a1[1]);
        fu.u[3] = cvtpk_bf16(a1[2], a1[3]);
        af[s] = fu.s8;
    }

    __syncthreads();

    floatx16 acc[4] = {};
    __builtin_amdgcn_s_setprio(1);
#pragma unroll
    for (int s = 0; s < 16; ++s) {
#pragma unroll
        for (int nt = 0; nt < 4; ++nt) {
            int n = nt * 32 + l31;
            int byte = (n * 512 + s * 32 + hi * 16) ^ ((n & 31) << 4);
            short8 bf = *(const short8*)((const char*)Bs + byte);
            acc[nt] = MFMA32(af[s], bf, acc[nt]);
        }
    }
    __builtin_amdgcn_s_setprio(0);

    int part = nb >> 1;   // 0=q, 1=k, 2=v
    if (part < 2) {
        ushort_t* dst = (part == 0) ? q : k;
#pragma unroll
        for (int nt = 0; nt < 4; ++nt) {
            int cc = (nb * 128 + nt * 32 + l31) & 255;
            int h = cc >> 6, d = cc & 63;
#pragma unroll
            for (int r = 0; r < 16; ++r) {
                int m = m0 + (r & 3) + 8 * (r >> 2) + 4 * hi;
                int bb = m >> 12, n = m & 4095;
                dst[((((int64_t)bb * HEADS + h) * SEQ) + n) * DHEAD + d] = f2bf(acc[nt][r]);
            }
        }
    } else {
#pragma unroll
        for (int nt = 0; nt < 4; ++nt) {
            int cc = (nb * 128 + nt * 32 + l31) & 255;
            int h = cc >> 6, d = cc & 63;
#pragma unroll
            for (int g = 0; g < 4; ++g) {
                int m = m0 + g * 8 + hi * 4;
                int bb = m >> 12, n = m & 4095;
                ushort4v pk;
#pragma unroll
                for (int r = 0; r < 4; ++r) pk[r] = f2bf(acc[nt][g * 4 + r]);
                *(ushort4v*)(v + ((((int64_t)bb * HEADS + h) * DHEAD) + d) * SEQ + n) = pk;
            }
        }
    }
}

// ---------------- stage 2: flash attention, T15 pipeline (defensive fences) ----------------
// grid = 512 (16 bh * 32 q-tiles of 128); 4 waves, each owns 32 q rows; KVBLK=128.
// Iter: [barrier] QK(it)+PV(it-1) cluster; [barrier] STAGE(it+1); softmax(it);
//       s_waitcnt vmcnt(0); [barrier].  sched_barrier(0) fences every barrier.
__global__ __launch_bounds__(256, 2) void attn_kernel(
    const ushort_t* __restrict__ Qg, const ushort_t* __restrict__ Kg,
    const ushort_t* __restrict__ Vtg, ushort_t* __restrict__ Og) {
    int bid = blockIdx.x;
    int swz = (bid & 7) * 64 + (bid >> 3);   // XCD-aware, bijective (512 % 8 == 0)
    int bh = swz >> 5;   // 0..15
    int qt = swz & 31;   // 0..31
    int tid = threadIdx.x;
    int wid = tid >> 6, lane = tid & 63;
    const int l31 = lane & 31;
    const int hi = lane >> 5;

    __shared__ ushort_t SM[2][16384] __attribute__((aligned(16)));  // 64 KB

    const ushort_t* qbase = Qg + (int64_t)bh * SEQ * DHEAD;
    const ushort_t* kbase = Kg + (int64_t)bh * SEQ * DHEAD;
    const ushort_t* vtbase = Vtg + (int64_t)bh * DHEAD * SEQ;

    int q0 = qt * 128 + wid * 32;
    short8 qf[4];
#pragma unroll
    for (int s = 0; s < 4; ++s)
        qf[s] = *(const short8*)(qbase + (int64_t)(q0 + l31) * DHEAD + s * 16 + hi * 8);

    const ushort_t* kp[4];
    const ushort_t* vp[4];
    ushort_t* kld[4];
    ushort_t* vld[4];
#pragma unroll
    for (int jj = 0; jj < 4; ++jj) {
        int L = jj * 256 + tid;
        int sl = L ^ ((L >> 7) & 7);   // involution
        int s_ = sl >> 8, hi_ = (sl >> 7) & 1, key_ = sl & 127;
        kp[jj] = kbase + key_ * DHEAD + s_ * 16 + hi_ * 8;
        int ks_ = sl >> 7, hik_ = (sl >> 6) & 1, d_ = sl & 63;
        vp[jj] = vtbase + (int64_t)d_ * SEQ + ks_ * 16 + hik_ * 8;
        kld[jj] = &SM[0][(jj * 256 + wid * 64) * 8];
        vld[jj] = &SM[0][8192 + (jj * 256 + wid * 64) * 8];
    }

#define STAGE(BUF)                                           \
    {                                                        \
        _Pragma("unroll") for (int jj = 0; jj < 4; ++jj) {   \
            gload_lds16(kp[jj], kld[jj] + (BUF) * 16384);    \
            gload_lds16(vp[jj], vld[jj] + (BUF) * 16384);    \
            kp[jj] += 128 * DHEAD;                           \
            vp[jj] += 128;                                   \
        }                                                    \
    }

    int bS[4];
#pragma unroll
    for (int s = 0; s < 4; ++s) bS[s] = hi * 2048 + ((l31 * 16) ^ ((s * 2 + hi) << 4));
    const int tV = hi * 1024 + l31 * 16;

    floatx16 accO[2] = {};
    floatx16 mseed = {};              // all elements = -m (running max, exp2-space)
    float l_i = 0.f;
    floatx16 accS[4];
    short8 pa[8];

#define QK_PHASE(SMC)                                                          \
    {                                                                          \
        _Pragma("unroll") for (int s = 0; s < 4; ++s) {                        \
            _Pragma("unroll") for (int kt = 0; kt < 4; ++kt) {                 \
                short8 kf = *(const short8*)((SMC) + bS[s] + s * 4096 + kt * 512); \
                accS[kt] = MFMA32(kf, qf[s], s == 0 ? mseed : accS[kt]);       \
            }                                                                  \
        }                                                                      \
    }

#define PV_PHASE(SMV)                                                          \
    {                                                                          \
        _Pragma("unroll") for (int ks = 0; ks < 8; ++ks) {                     \
            int va = tV ^ (ks << 4);                                           \
            _Pragma("unroll") for (int o = 0; o < 2; ++o) {                    \
                short8 vf = *(const short8*)((SMV) + va + ks * 2048 + o * 512);\
                accO[o] = MFMA32(pa[ks], vf, accO[o]);                         \
            }                                                                  \
        }                                                                      \
    }

#define SOFTMAX_PACK()                                                         \
    {                                                                          \
        float mk[4];                                                           \
        _Pragma("unroll") for (int kt = 0; kt < 4; ++kt) {                     \
            float t0 = max3f(accS[kt][0], accS[kt][1], accS[kt][2]);           \
            t0 = max3f(t0, accS[kt][3], accS[kt][4]);                          \
            t0 = max3f(t0, accS[kt][5], accS[kt][6]);                          \
            t0 = max3f(t0, accS[kt][7], accS[kt][8]);                          \
            t0 = max3f(t0, accS[kt][9], accS[kt][10]);                         \
            t0 = max3f(t0, accS[kt][11], accS[kt][12]);                        \
            t0 = max3f(t0, accS[kt][13], accS[kt][14]);                        \
            mk[kt] = fmaxf(t0, accS[kt][15]);                                  \
        }                                                                      \
        float mx = fmaxf(max3f(mk[0], mk[1], mk[2]), mk[3]);                   \
        mx = fmaxf(mx, __shfl_xor(mx, 32, 64));                                \
        if (!__all(mx <= 8.f)) {                                               \
            float mb = fmaxf(mx, 0.f);                                         \
            float corr = exp2_fast(-mb);                                       \
            l_i *= corr;                                                       \
            _Pragma("unroll") for (int r = 0; r < 16; ++r) {                   \
                int qr = (r & 3) + 8 * (r >> 2) + 4 * hi;                      \
                float cr = __shfl(corr, qr, 64);                               \
                accO[0][r] *= cr;                                              \
                accO[1][r] *= cr;                                              \
            }                                                                  \
            _Pragma("unroll") for (int r = 0; r < 16; ++r) mseed[r] -= mb;     \
            _Pragma("unroll") for (int kt = 0; kt < 4; ++kt)                   \
                _Pragma("unroll") for (int r = 0; r < 16; ++r)                 \
                    accS[kt][r] -= mb;                                         \
        }                                                                      \
        float rs0 = 0.f, rs1 = 0.f, rs2 = 0.f, rs3 = 0.f;                      \
        _Pragma("unroll") for (int r = 0; r < 16; ++r) {                       \
            float e0 = exp2_fast(accS[0][r]);                                  \
            float e1 = exp2_fast(accS[1][r]);                                  \
            float e2 = exp2_fast(accS[2][r]);                                  \
            float e3 = exp2_fast(accS[3][r]);                                  \
            accS[0][r] = e0;                                                   \
            accS[1][r] = e1;                                                   \
            accS[2][r] = e2;                                                   \
            accS[3][r] = e3;                                                   \
            rs0 += e0;                                                         \
            rs1 += e1;                                                         \
            rs2 += e2;                                                         \
            rs3 += e3;                                                         \
        }                                                                      \
        float rs = (rs0 + rs1) + (rs2 + rs3);                                  \
        rs += __shfl_xor(rs, 32, 64);                                          \
        l_i += rs;                                                             \
        _Pragma("unroll") for (int kt = 0; kt < 4; ++kt) {                     \
            unsigned w0 = cvtpk_bf16(accS[kt][0], accS[kt][1]);                \
            unsigned w1 = cvtpk_bf16(accS[kt][2], accS[kt][3]);                \
            unsigned w2 = cvtpk_bf16(accS[kt][4], accS[kt][5]);                \
            unsigned w3 = cvtpk_bf16(accS[kt][6], accS[kt][7]);                \
            unsigned w4 = cvtpk_bf16(accS[kt][8], accS[kt][9]);                \
            unsigned w5 = cvtpk_bf16(accS[kt][10], accS[kt][11]);              \
            unsigned w6 = cvtpk_bf16(accS[kt][12], accS[kt][13]);              \
            unsigned w7 = cvtpk_bf16(accS[kt][14], accS[kt][15]);              \
            plswap(w0, w2);                                                    \
            plswap(w1, w3);                                                    \
            plswap(w4, w6);                                                    \
            plswap(w5, w7);                                                    \
            union { unsigned u[4]; short8 s; } f0, f1;                         \
            f0.u[0] = w0; f0.u[1] = w1; f0.u[2] = w2; f0.u[3] = w3;            \
            f1.u[0] = w4; f1.u[1] = w5; f1.u[2] = w6; f1.u[3] = w7;            \
            pa[2 * kt] = f0.s;                                                 \
            pa[2 * kt + 1] = f1.s;                                             \
        }                                                                      \
    }

#define VMFENCE()                                                              \
    asm volatile("s_waitcnt vmcnt(0)" ::: "memory");                           \
    __builtin_amdgcn_sched_barrier(0)

#define SBAR()                                                                 \
    __builtin_amdgcn_sched_barrier(0);                                         \
    __syncthreads();                                                           \
    __builtin_amdgcn_sched_barrier(0)

// one T15 iteration: QK(it) from SMC, PV(it-1) from SMV; stage tile it+1 into SBUF.
#define ITER(SMC_OFF, SMV_OFF, SBUF, DO_STAGE)                                 \
    {                                                                          \
        __builtin_amdgcn_s_setprio(1);                                         \
        QK_PHASE((const char*)SM + (SMC_OFF));                                 \
        PV_PHASE((const char*)SM + (SMV_OFF));                                 \
        __builtin_amdgcn_s_setprio(0);                                         \
        SBAR();           /* all waves done reading both buffers */            \
        if (DO_STAGE) { STAGE(SBUF); }                                         \
        SOFTMAX_PACK();                                                        \
        VMFENCE();        /* own staged loads landed */                        \
        SBAR();           /* staged tile visible to all waves */               \
    }

    // ---- prologue: tiles 0 and 1 ----
    STAGE(0);
    VMFENCE();
    SBAR();
    STAGE(1);
    QK_PHASE((const char*)SM);   // QK(0) from buf0 (buf1 writes disjoint)
    SOFTMAX_PACK();              // pa = P(0)
    VMFENCE();
    SBAR();                      // tile 1 visible

    // ---- steady state: it = 1..30 as 15 unrolled pairs, it = 31 peeled ----
#pragma unroll 1
    for (int p = 0; p < 15; ++p) {
        ITER(32768, 16384, 0, true);           // odd it: QK buf1, PV buf0.V, stage->buf0
        ITER(0, 32768 + 16384, 1, true);       // even it: QK buf0, PV buf1.V, stage->buf1
    }
    ITER(32768, 16384, 0, false);              // it=31: QK buf1, PV buf0.V, no stage
    PV_PHASE((const char*)SM + 32768 + 16384); // PV(31) from buf1.V

    // --- epilogue: normalize, write O as [b, n, h*64+d] bf16 ---
    int b = bh >> 2, h = bh & 3;
    float invl = 1.f / l_i;
#pragma unroll
    for (int r = 0; r < 16; ++r) {
        int qr = (r & 3) + 8 * (r >> 2) + 4 * hi;
        float inv = __shfl(invl, qr, 64);
        int n = q0 + qr;
#pragma unroll
        for (int o = 0; o < 2; ++o) {
            int d = o * 32 + l31;
            Og[((int64_t)b * SEQ + n) * INNER + h * 64 + d] = f2bf(accO[o][r] * inv);
        }
    }
#undef STAGE
#undef QK_PHASE
#undef PV_PHASE
#undef SOFTMAX_PACK
#undef VMFENCE
#undef SBAR
#undef ITER
}

// ---------------- stage 3: out = O @ w_out^T + b_out (block-tiled, LDS-staged B) --------
__global__ __launch_bounds__(256) void proj_gemm(
    const ushort_t* __restrict__ A, const ushort_t* __restrict__ B,
    const float* __restrict__ bias, float* __restrict__ out) {
    __shared__ ushort_t Bs[128 * 256] __attribute__((aligned(16)));  // 64 KB
    int bid = blockIdx.x;
    int swz = (bid & 7) * 64 + (bid >> 3);   // 512 = 8 * 64
    int mt = swz >> 1, nb = swz & 1;
    int tid = threadIdx.x;
    int wid = tid >> 6, lane = tid & 63;
    const int l31 = lane & 31, hi = lane >> 5;

    const ushort_t* bsrc = B + (int64_t)nb * 128 * 256;
#pragma unroll
    for (int i = 0; i < 16; ++i) {
        int L = i * 256 + tid;
        int sl = L ^ ((L >> 5) & 31);
        gload_lds16(bsrc + (sl >> 5) * 256 + (sl & 31) * 8, &Bs[L * 8]);
    }

    int m0 = mt * 64 + (wid & 1) * 32;
    int nside = wid >> 1;
    const ushort_t* abase = A + (int64_t)(m0 + l31) * 256 + hi * 8;
    short8 af[16];
#pragma unroll
    for (int s = 0; s < 16; ++s) af[s] = *(const short8*)(abase + s * 16);

    __syncthreads();

    floatx16 acc[2] = {};
    __builtin_amdgcn_s_setprio(1);
#pragma unroll
    for (int s = 0; s < 16; ++s) {
#pragma unroll
        for (int nt = 0; nt < 2; ++nt) {
            int n = nside * 64 + nt * 32 + l31;
            int byte = (n * 512 + s * 32 + hi * 16) ^ ((n & 31) << 4);
            short8 bf = *(const short8*)((const char*)Bs + byte);
            acc[nt] = MFMA32(af[s], bf, acc[nt]);
        }
    }
    __builtin_amdgcn_s_setprio(0);

#pragma unroll
    for (int nt = 0; nt < 2; ++nt) {
        int col = nb * 128 + nside * 64 + nt * 32 + l31;
        float bv = bias[col];
#pragma unroll
        for (int r = 0; r < 16; ++r) {
            int m = m0 + (r & 3) + 8 * (r >> 2) + 4 * hi;
            out[(int64_t)m * DIM + col] = acc[nt][r] + bv;
        }
    }
}

extern "C" void kernel_launch(void* const* d_in, const int* in_sizes, int n_in,
                              void* d_out, int out_size, void* d_ws, size_t ws_size,
                              hipStream_t stream) {
    const float* x = (const float*)d_in[0];
    const float* w_qkv = (const float*)d_in[1];
    const float* w_out = (const float*)d_in[2];
    const float* b_out = (const float*)d_in[3];
    float* out = (float*)d_out;

    ushort_t* ws = (ushort_t*)d_ws;
    const int64_t NW = (int64_t)NQKV * DIM;        // 196608
    const int64_t NO = (int64_t)DIM * INNER;       // 65536
    const int64_t NH = (int64_t)BATCH * HEADS * SEQ * DHEAD;  // 4194304
    ushort_t* wqkvb = ws;
    ushort_t* woutb = wqkvb + NW;
    ushort_t* qb = woutb + NO;
    ushort_t* kb = qb + NH;
    ushort_t* vb = kb + NH;      // V^T layout [b,h,d,n]
    ushort_t* ob = vb + NH;

    convert_w<<<256, 256, 0, stream>>>(w_qkv, w_out, wqkvb, woutb);
    qkv_gemm<<<768, 256, 0, stream>>>(x, wqkvb, qb, kb, vb);
    attn_kernel<<<512, 256, 0, stream>>>(qb, kb, vb, ob);
    proj_gemm<<<512, 256, 0, stream>>>(ob, woutb, b_out, out);
}